// Round 7
// baseline (77.727 us; speedup 1.0000x reference)
//
#include <hip/hip_runtime.h>
#include <hip/hip_bf16.h>
#include <stdint.h>

#define TOKENS 4096
#define DIN 1024
#define DOUT 1024
#define RANK 8
#define BM 64
#define BN 64
#define BK 64

typedef __attribute__((ext_vector_type(4))) float f32x4;
typedef __attribute__((ext_vector_type(8))) short short8;

__device__ __forceinline__ unsigned short f2bf(float f) {
    union { float f; unsigned u; } v; v.f = f;
    unsigned r = v.u + 0x7FFFu + ((v.u >> 16) & 1u);
    return (unsigned short)(r >> 16);
}

// W [DOUT][DIN] fp32 -> bf16
__global__ __launch_bounds__(256) void k_convert_w(const float* __restrict__ W,
                                                   ushort* __restrict__ Wb) {
    int i = blockIdx.x * 256 + threadIdx.x;
    float4 v = ((const float4*)W)[i];
    ushort4 u;
    u.x = f2bf(v.x); u.y = f2bf(v.y); u.z = f2bf(v.z); u.w = f2bf(v.w);
    ((ushort4*)Wb)[i] = u;
}

// One block per token t: inter[t][r] = dot(x[t,:], B[t,r,:]); xb = bf16(x)
__global__ __launch_bounds__(256) void k_inter(const float* __restrict__ x,
                                               const float* __restrict__ Bp,
                                               float* __restrict__ inter,
                                               ushort* __restrict__ xb) {
    const int t = blockIdx.x;
    const int tid = threadIdx.x;
    const int lane = tid & 63, wave = tid >> 6;

    float4 xv = ((const float4*)(x + (size_t)t * DIN))[tid];

    ushort4 u;
    u.x = f2bf(xv.x); u.y = f2bf(xv.y); u.z = f2bf(xv.z); u.w = f2bf(xv.w);
    ((ushort4*)(xb + (size_t)t * DIN))[tid] = u;

    const float4* B4 = (const float4*)(Bp + (size_t)t * RANK * DIN);
    float acc[RANK];
#pragma unroll
    for (int r = 0; r < RANK; ++r) {
        float4 bv = B4[r * 256 + tid];
        acc[r] = xv.x * bv.x + xv.y * bv.y + xv.z * bv.z + xv.w * bv.w;
    }

    __shared__ float part[4][RANK];
#pragma unroll
    for (int r = 0; r < RANK; ++r) {
        float v = acc[r];
#pragma unroll
        for (int off = 32; off > 0; off >>= 1) v += __shfl_xor(v, off, 64);
        if (lane == 0) part[wave][r] = v;
    }
    __syncthreads();
    if (tid < RANK)
        inter[(size_t)t * RANK + tid] =
            part[0][tid] + part[1][tid] + part[2][tid] + part[3][tid];
}

// out[m,o] = bias[o] + Xb@Wb^T (bf16 MFMA) + sum_r inter[m,r]*A[m,o,r]
// BM=BN=64 -> grid 1024 = 4 blocks/CU: TLP (staggered independent blocks)
// hides the per-iter drain instead of intra-block pipelining (R6 showed that
// was neutral at 2 blocks/CU). 4 waves 2x2, each wave a 32x32 quadrant
// (2x2 16x16 frags). A-stream interleaved: 1 output element (32B) per iter,
// accumulated into acc at static indices (full unroll).
__global__ __launch_bounds__(256, 4) void k_gemm_fused(const ushort* __restrict__ Xb,
                                                       const ushort* __restrict__ Wb,
                                                       const float* __restrict__ bias,
                                                       const float* __restrict__ inter,
                                                       const float* __restrict__ Ap,
                                                       float* __restrict__ out) {
    __shared__ ushort As[BM * BK];      // 8 KB [m][k]
    __shared__ ushort Bs[BN * BK];      // 8 KB [o][k]
    __shared__ float sInter[BM * 8];    // 2 KB
    __shared__ float sBias[BN];

    const int tid = threadIdx.x;
    const int lane = tid & 63, wave = tid >> 6;
    const int wm = wave >> 1, wn = wave & 1;

    // XCD-aware bijective swizzle (1024 blocks, 1024%8==0): each XCD gets
    // 128 consecutive swz = 8 M-panels x 16 N-groups -> Xb 1MB + Wb 2MB in L2.
    const int bid = blockIdx.x;
    const int swz = (bid & 7) * 128 + (bid >> 3);
    const int M0 = (swz >> 4) * BM;
    const int N0 = (swz & 15) * BN;

    const int col16 = lane & 15;
    const int kg = lane >> 4;

    // Stage inter tile (64 tokens x 8) + bias. Visible after first barrier.
    if (tid < 128) ((float4*)sInter)[tid] = ((const float4*)(inter + (size_t)M0 * RANK))[tid];
    if (tid < 16) ((float4*)sBias)[tid] = ((const float4*)(bias + N0))[tid];

    const float* Abase = Ap + ((size_t)(M0 + wm * 32 + kg * 4) * DOUT +
                               (N0 + wn * 32 + col16)) * RANK;

    f32x4 acc[2][2] = {};

#pragma unroll
    for (int it = 0; it < 16; ++it) {
        const int kt = it * BK;
        __syncthreads();  // previous iter's LDS reads done -> safe to overwrite
#pragma unroll
        for (int st = 0; st < 2; ++st) {
            int flat = st * 256 + tid;           // 64 rows x 8 chunks of 16B
            int row = flat >> 3, ch = flat & 7;
            const ushort* g = Xb + (size_t)(M0 + row) * DIN + kt + ch * 8;
            __builtin_amdgcn_global_load_lds(
                (const __attribute__((address_space(1))) void*)g,
                (__attribute__((address_space(3))) void*)(As + flat * 8), 16, 0, 0);
        }
#pragma unroll
        for (int st = 0; st < 2; ++st) {
            int flat = st * 256 + tid;
            int row = flat >> 3, ch = flat & 7;
            const ushort* g = Wb + (size_t)(N0 + row) * DIN + kt + ch * 8;
            __builtin_amdgcn_global_load_lds(
                (const __attribute__((address_space(1))) void*)g,
                (__attribute__((address_space(3))) void*)(Bs + flat * 8), 16, 0, 0);
        }

        // A-slice: one output element e = it (nf = it>>3, mf = (it>>2)&1,
        // rg = it&3). 32B contiguous per thread, 512B per 16-lane group.
        const int nf = it >> 3, mf = (it >> 2) & 1, rg = it & 3;
        const float4* Ae = (const float4*)(Abase + ((size_t)(mf * 16 + rg) * DOUT + nf * 16) * RANK);
        float4 a0 = Ae[0], a1 = Ae[1];

        __syncthreads();  // drains vmcnt (stage + A) then barrier -> LDS ready

#pragma unroll
        for (int ks = 0; ks < 2; ++ks) {
            short8 a[2], b[2];
#pragma unroll
            for (int m2 = 0; m2 < 2; ++m2)
                a[m2] = *(const short8*)(As + (wm * 32 + m2 * 16 + col16) * BK + ks * 32 + kg * 8);
#pragma unroll
            for (int n2 = 0; n2 < 2; ++n2)
                b[n2] = *(const short8*)(Bs + (wn * 32 + n2 * 16 + col16) * BK + ks * 32 + kg * 8);
#pragma unroll
            for (int m2 = 0; m2 < 2; ++m2)
#pragma unroll
                for (int n2 = 0; n2 < 2; ++n2)
                    acc[m2][n2] = __builtin_amdgcn_mfma_f32_16x16x32_bf16(
                        a[m2], b[n2], acc[m2][n2], 0, 0, 0);
        }

        // Adaptation dot for element e, straight into acc (static indices).
        const int mloc = wm * 32 + mf * 16 + kg * 4 + rg;
        const float4* iv = (const float4*)(sInter + mloc * 8);
        float4 i0 = iv[0], i1 = iv[1];
        float d = a0.x * i0.x + a0.y * i0.y + a0.z * i0.z + a0.w * i0.w +
                  a1.x * i1.x + a1.y * i1.y + a1.z * i1.z + a1.w * i1.w;
        acc[mf][nf][rg] += d;
    }

    // Epilogue: single write of out.
#pragma unroll
    for (int nf = 0; nf < 2; ++nf) {
        const int oc = wn * 32 + nf * 16 + col16;
        const int o = N0 + oc;
        const float bb = sBias[oc];
#pragma unroll
        for (int mf = 0; mf < 2; ++mf) {
#pragma unroll
            for (int rg = 0; rg < 4; ++rg) {
                const int m = M0 + wm * 32 + mf * 16 + kg * 4 + rg;
                out[(size_t)m * DOUT + o] = acc[mf][nf][rg] + bb;
            }
        }
    }
}

extern "C" void kernel_launch(void* const* d_in, const int* in_sizes, int n_in,
                              void* d_out, int out_size, void* d_ws, size_t ws_size,
                              hipStream_t stream) {
    const float* x    = (const float*)d_in[0];
    const float* Ap   = (const float*)d_in[1];
    const float* Bp   = (const float*)d_in[2];
    const float* W    = (const float*)d_in[3];
    const float* bias = (const float*)d_in[4];
    float* out = (float*)d_out;

    // ws: xb (8 MB) | Wb (2 MB) | inter (128 KB)
    ushort* xb = (ushort*)d_ws;
    ushort* Wb = xb + (size_t)TOKENS * DIN;
    float* inter = (float*)(Wb + (size_t)DOUT * DIN);

    hipLaunchKernelGGL(k_convert_w, dim3(DOUT * DIN / 1024), dim3(256), 0, stream, W, Wb);
    hipLaunchKernelGGL(k_inter, dim3(TOKENS), dim3(256), 0, stream, x, Bp, inter, xb);
    hipLaunchKernelGGL(k_gemm_fused, dim3((TOKENS / BM) * (DOUT / BN)), dim3(256), 0, stream,
                       xb, Wb, bias, inter, Ap, out);
}

// Round 9
// 74.633 us; speedup vs baseline: 1.0414x; 1.0414x over previous
//
#include <hip/hip_runtime.h>
#include <hip/hip_bf16.h>
#include <stdint.h>

#define TOKENS 4096
#define DIN 1024
#define DOUT 1024
#define RANK 8
#define BM 128
#define BN 64
#define BK 64

typedef __attribute__((ext_vector_type(4))) float f32x4;
typedef __attribute__((ext_vector_type(8))) short short8;

__device__ __forceinline__ unsigned short f2bf(float f) {
    union { float f; unsigned u; } v; v.f = f;
    unsigned r = v.u + 0x7FFFu + ((v.u >> 16) & 1u);
    return (unsigned short)(r >> 16);
}

// W [DOUT][DIN] fp32 -> bf16
__global__ __launch_bounds__(256) void k_convert_w(const float* __restrict__ W,
                                                   ushort* __restrict__ Wb) {
    int i = blockIdx.x * 256 + threadIdx.x;
    float4 v = ((const float4*)W)[i];
    ushort4 u;
    u.x = f2bf(v.x); u.y = f2bf(v.y); u.z = f2bf(v.z); u.w = f2bf(v.w);
    ((ushort4*)Wb)[i] = u;
}

// One block per token t: inter[t][r] = dot(x[t,:], B[t,r,:]); xb = bf16(x)
__global__ __launch_bounds__(256) void k_inter(const float* __restrict__ x,
                                               const float* __restrict__ Bp,
                                               float* __restrict__ inter,
                                               ushort* __restrict__ xb) {
    const int t = blockIdx.x;
    const int tid = threadIdx.x;
    const int lane = tid & 63, wave = tid >> 6;

    float4 xv = ((const float4*)(x + (size_t)t * DIN))[tid];

    ushort4 u;
    u.x = f2bf(xv.x); u.y = f2bf(xv.y); u.z = f2bf(xv.z); u.w = f2bf(xv.w);
    ((ushort4*)(xb + (size_t)t * DIN))[tid] = u;

    const float4* B4 = (const float4*)(Bp + (size_t)t * RANK * DIN);
    float acc[RANK];
#pragma unroll
    for (int r = 0; r < RANK; ++r) {
        float4 bv = B4[r * 256 + tid];
        acc[r] = xv.x * bv.x + xv.y * bv.y + xv.z * bv.z + xv.w * bv.w;
    }

    __shared__ float part[4][RANK];
#pragma unroll
    for (int r = 0; r < RANK; ++r) {
        float v = acc[r];
#pragma unroll
        for (int off = 32; off > 0; off >>= 1) v += __shfl_xor(v, off, 64);
        if (lane == 0) part[wave][r] = v;
    }
    __syncthreads();
    if (tid < RANK)
        inter[(size_t)t * RANK + tid] =
            part[0][tid] + part[1][tid] + part[2][tid] + part[3][tid];
}

// out[m,o] = bias[o] + Xb@Wb^T (bf16 MFMA) + sum_r inter[m,r]*A[m,o,r]
// Counted-vmcnt pipeline, ORDER-PINNED (R8 fix): per iter issue A(t+1) FIRST,
// sched_barrier(0), then stage(t+1); wait vmcnt(10) = retire A(t)+stage(t),
// keep the 10 newest (next A + next stage) in flight across both barriers.
// Never vmcnt(0) inside the loop; barrier #2 is a pure s_barrier.
__global__ __launch_bounds__(256, 2) void k_gemm_fused(const ushort* __restrict__ Xb,
                                                       const ushort* __restrict__ Wb,
                                                       const float* __restrict__ bias,
                                                       const float* __restrict__ inter,
                                                       const float* __restrict__ Ap,
                                                       float* __restrict__ out) {
    __shared__ ushort As[2][BM * BK];   // 2 x 16 KB
    __shared__ ushort Bs[2][BN * BK];   // 2 x 8 KB
    __shared__ float sInter[BM * 8];    // 4 KB
    __shared__ float sBias[BN];

    const int tid = threadIdx.x;
    const int lane = tid & 63, wave = tid >> 6;
    const int wm = wave >> 1, wn = wave & 1;

    // XCD-aware bijective swizzle (512 % 8 == 0).
    const int bid = blockIdx.x;
    const int swz = (bid & 7) * 64 + (bid >> 3);
    const int M0 = (swz >> 4) * BM;
    const int N0 = (swz & 15) * BN;

    const int col16 = lane & 15;
    const int kg = lane >> 4;

    // Stage inter tile + bias (compiler drains these loads before ds_write;
    // ds_writes covered by t=0's lgkmcnt(0)).
    ((float4*)sInter)[tid] = ((const float4*)(inter + (size_t)M0 * RANK))[tid];
    if (tid < 16) ((float4*)sBias)[tid] = ((const float4*)(bias + N0))[tid];

    const float* Abase = Ap + ((size_t)(M0 + wm * 64 + kg * 4) * DOUT +
                               (N0 + wn * 32 + col16)) * RANK;

    auto stage = [&](int b, int kt) {
#pragma unroll
        for (int st = 0; st < 4; ++st) {
            int flat = st * 256 + tid;           // 128 rows x 8 chunks of 16B
            int row = flat >> 3, ch = flat & 7;
            const ushort* g = Xb + (size_t)(M0 + row) * DIN + kt + ch * 8;
            __builtin_amdgcn_global_load_lds(
                (const __attribute__((address_space(1))) void*)g,
                (__attribute__((address_space(3))) void*)(&As[b][flat * 8]), 16, 0, 0);
        }
#pragma unroll
        for (int st = 0; st < 2; ++st) {
            int flat = st * 256 + tid;           // 64 rows x 8 chunks
            int row = flat >> 3, ch = flat & 7;
            const ushort* g = Wb + (size_t)(N0 + row) * DIN + kt + ch * 8;
            __builtin_amdgcn_global_load_lds(
                (const __attribute__((address_space(1))) void*)g,
                (__attribute__((address_space(3))) void*)(&Bs[b][flat * 8]), 16, 0, 0);
        }
    };

    // A-row base for iter e (elements 2e, 2e+1).
    auto aptr = [&](int e) {
        const int nf = e >> 3, mf = (e >> 1) & 3, rg0 = (e & 1) * 2;
        return Abase + ((size_t)(mf * 16 + rg0) * DOUT + nf * 16) * RANK;
    };

    float4 areg[2][4];

    // Prologue: A(0) FIRST, then stage(0) — pinned.
    {
        const float* Ae0 = aptr(0);
        areg[0][0] = ((const float4*)Ae0)[0];
        areg[0][1] = ((const float4*)Ae0)[1];
        areg[0][2] = ((const float4*)(Ae0 + (size_t)DOUT * RANK))[0];
        areg[0][3] = ((const float4*)(Ae0 + (size_t)DOUT * RANK))[1];
    }
    __builtin_amdgcn_sched_barrier(0);
    stage(0, 0);

    f32x4 acc[4][2] = {};

#pragma unroll
    for (int t = 0; t < 16; ++t) {
        const int cur = t & 1;

        if (t < 15) {
            // A(t+1) first...
            const float* Ae0 = aptr(t + 1);
            areg[cur ^ 1][0] = ((const float4*)Ae0)[0];
            areg[cur ^ 1][1] = ((const float4*)Ae0)[1];
            areg[cur ^ 1][2] = ((const float4*)(Ae0 + (size_t)DOUT * RANK))[0];
            areg[cur ^ 1][3] = ((const float4*)(Ae0 + (size_t)DOUT * RANK))[1];
            __builtin_amdgcn_sched_barrier(0);
            // ...then stage(t+1). Outstanding order is now
            // [A(t)4, stage(t)6, A(t+1)4, stage(t+1)6].
            stage(cur ^ 1, (t + 1) * BK);
        }

        if (t == 0) {
            asm volatile("s_waitcnt vmcnt(10) lgkmcnt(0)" ::: "memory");
        } else if (t < 15) {
            asm volatile("s_waitcnt vmcnt(10)" ::: "memory");
        } else {
            asm volatile("s_waitcnt vmcnt(0)" ::: "memory");
        }
        __builtin_amdgcn_s_barrier();

        // MFMA on buf[cur].
#pragma unroll
        for (int ks = 0; ks < 2; ++ks) {
            short8 a[4], b[2];
#pragma unroll
            for (int m4 = 0; m4 < 4; ++m4)
                a[m4] = *(const short8*)(&As[cur][(wm * 64 + m4 * 16 + col16) * BK + ks * 32 + kg * 8]);
#pragma unroll
            for (int n2 = 0; n2 < 2; ++n2)
                b[n2] = *(const short8*)(&Bs[cur][(wn * 32 + n2 * 16 + col16) * BK + ks * 32 + kg * 8]);
#pragma unroll
            for (int m4 = 0; m4 < 4; ++m4)
#pragma unroll
                for (int n2 = 0; n2 < 2; ++n2)
                    acc[m4][n2] = __builtin_amdgcn_mfma_f32_16x16x32_bf16(
                        a[m4], b[n2], acc[m4][n2], 0, 0, 0);
        }

        // Adaptation dot for elements 2t, 2t+1 (areg[cur] already retired by
        // the vmcnt(10); compiler's own wait here is counted, not a drain).
        {
            const int nf = t >> 3, mf = (t >> 1) & 3, rg0 = (t & 1) * 2;
            const int mloc0 = wm * 64 + mf * 16 + kg * 4 + rg0;
            const float4* iv0 = (const float4*)(sInter + mloc0 * 8);
            const float4* iv1 = (const float4*)(sInter + (mloc0 + 1) * 8);
            float4 i00 = iv0[0], i01 = iv0[1], i10 = iv1[0], i11 = iv1[1];
            float4 a00 = areg[cur][0], a01 = areg[cur][1];
            float4 a10 = areg[cur][2], a11 = areg[cur][3];
            float d0 = a00.x * i00.x + a00.y * i00.y + a00.z * i00.z + a00.w * i00.w +
                       a01.x * i01.x + a01.y * i01.y + a01.z * i01.z + a01.w * i01.w;
            float d1 = a10.x * i10.x + a10.y * i10.y + a10.z * i10.z + a10.w * i10.w +
                       a11.x * i11.x + a11.y * i11.y + a11.z * i11.z + a11.w * i11.w;
            acc[mf][nf][rg0] += d0;
            acc[mf][nf][rg0 + 1] += d1;
        }

        // Protect buf[cur] from iter t+1's stage overwrite. Pure exec sync.
        __builtin_amdgcn_s_barrier();
    }

    // Epilogue: single write of out.
#pragma unroll
    for (int nf = 0; nf < 2; ++nf) {
        const int oc = wn * 32 + nf * 16 + col16;
        const int o = N0 + oc;
        const float bb = sBias[oc];
#pragma unroll
        for (int mf = 0; mf < 4; ++mf) {
#pragma unroll
            for (int rg = 0; rg < 4; ++rg) {
                const int m = M0 + wm * 64 + mf * 16 + kg * 4 + rg;
                out[(size_t)m * DOUT + o] = acc[mf][nf][rg] + bb;
            }
        }
    }
}

extern "C" void kernel_launch(void* const* d_in, const int* in_sizes, int n_in,
                              void* d_out, int out_size, void* d_ws, size_t ws_size,
                              hipStream_t stream) {
    const float* x    = (const float*)d_in[0];
    const float* Ap   = (const float*)d_in[1];
    const float* Bp   = (const float*)d_in[2];
    const float* W    = (const float*)d_in[3];
    const float* bias = (const float*)d_in[4];
    float* out = (float*)d_out;

    // ws: xb (8 MB) | Wb (2 MB) | inter (128 KB)
    ushort* xb = (ushort*)d_ws;
    ushort* Wb = xb + (size_t)TOKENS * DIN;
    float* inter = (float*)(Wb + (size_t)DOUT * DIN);

    hipLaunchKernelGGL(k_convert_w, dim3(DOUT * DIN / 1024), dim3(256), 0, stream, W, Wb);
    hipLaunchKernelGGL(k_inter, dim3(TOKENS), dim3(256), 0, stream, x, Bp, inter, xb);
    hipLaunchKernelGGL(k_gemm_fused, dim3((TOKENS / BM) * (DOUT / BN)), dim3(256), 0, stream,
                       xb, Wb, bias, inter, Ap, out);
}

// Round 10
// 73.486 us; speedup vs baseline: 1.0577x; 1.0156x over previous
//
#include <hip/hip_runtime.h>
#include <hip/hip_bf16.h>
#include <stdint.h>

#define TOKENS 4096
#define DIN 1024
#define DOUT 1024
#define RANK 8
#define BM 128
#define BN 64
#define BK 64

typedef __attribute__((ext_vector_type(4))) float f32x4;
typedef __attribute__((ext_vector_type(8))) short short8;

__device__ __forceinline__ unsigned short f2bf(float f) {
    union { float f; unsigned u; } v; v.f = f;
    unsigned r = v.u + 0x7FFFu + ((v.u >> 16) & 1u);
    return (unsigned short)(r >> 16);
}

// W [DOUT][DIN] fp32 -> bf16
__global__ __launch_bounds__(256) void k_convert_w(const float* __restrict__ W,
                                                   ushort* __restrict__ Wb) {
    int i = blockIdx.x * 256 + threadIdx.x;
    float4 v = ((const float4*)W)[i];
    ushort4 u;
    u.x = f2bf(v.x); u.y = f2bf(v.y); u.z = f2bf(v.z); u.w = f2bf(v.w);
    ((ushort4*)Wb)[i] = u;
}

// One block per token t: inter[t][r] = dot(x[t,:], B[t,r,:]); xb = bf16(x)
__global__ __launch_bounds__(256) void k_inter(const float* __restrict__ x,
                                               const float* __restrict__ Bp,
                                               float* __restrict__ inter,
                                               ushort* __restrict__ xb) {
    const int t = blockIdx.x;
    const int tid = threadIdx.x;
    const int lane = tid & 63, wave = tid >> 6;

    float4 xv = ((const float4*)(x + (size_t)t * DIN))[tid];

    ushort4 u;
    u.x = f2bf(xv.x); u.y = f2bf(xv.y); u.z = f2bf(xv.z); u.w = f2bf(xv.w);
    ((ushort4*)(xb + (size_t)t * DIN))[tid] = u;

    const float4* B4 = (const float4*)(Bp + (size_t)t * RANK * DIN);
    float acc[RANK];
#pragma unroll
    for (int r = 0; r < RANK; ++r) {
        float4 bv = B4[r * 256 + tid];
        acc[r] = xv.x * bv.x + xv.y * bv.y + xv.z * bv.z + xv.w * bv.w;
    }

    __shared__ float part[4][RANK];
#pragma unroll
    for (int r = 0; r < RANK; ++r) {
        float v = acc[r];
#pragma unroll
        for (int off = 32; off > 0; off >>= 1) v += __shfl_xor(v, off, 64);
        if (lane == 0) part[wave][r] = v;
    }
    __syncthreads();
    if (tid < RANK)
        inter[(size_t)t * RANK + tid] =
            part[0][tid] + part[1][tid] + part[2][tid] + part[3][tid];
}

// out[m,o] = bias[o] + Xb@Wb^T (bf16 MFMA) + sum_r inter[m,r]*A[m,o,r]
// R6-proven structure (dbuf, A-interleave, XCD swizzle) + T2 LDS XOR-swizzle:
// [row][64] bf16 rows are 128 B -> ds_read_b128 across 16 rows was a ~16-way
// bank conflict (all rows land on the same 4-bank group; row*128/4 % 32 == 0).
// Fix per rule 21 (gload_lds writes linearly): fetch global chunk ch^(row&7)
// into linear LDS slot ch, and read with chs = (ks*4+kg) ^ (col16&7) ->
// 16 lanes spread over 8 slots / 32 banks = conflict-free.
__global__ __launch_bounds__(256, 3) void k_gemm_fused(const ushort* __restrict__ Xb,
                                                       const ushort* __restrict__ Wb,
                                                       const float* __restrict__ bias,
                                                       const float* __restrict__ inter,
                                                       const float* __restrict__ Ap,
                                                       float* __restrict__ out) {
    __shared__ ushort As[2][BM * BK];   // 2 x 16 KB
    __shared__ ushort Bs[2][BN * BK];   // 2 x 8 KB
    __shared__ float sInter[BM * 8];    // 4 KB
    __shared__ float sBias[BN];

    const int tid = threadIdx.x;
    const int lane = tid & 63, wave = tid >> 6;
    const int wm = wave >> 1, wn = wave & 1;

    // XCD-aware bijective swizzle (512 % 8 == 0).
    const int bid = blockIdx.x;
    const int swz = (bid & 7) * 64 + (bid >> 3);
    const int M0 = (swz >> 4) * BM;
    const int N0 = (swz & 15) * BN;

    const int col16 = lane & 15;
    const int kg = lane >> 4;
    const int c8 = col16 & 7;

    // Stage inter tile + bias into LDS.
    ((float4*)sInter)[tid] = ((const float4*)(inter + (size_t)M0 * RANK))[tid];
    if (tid < 16) ((float4*)sBias)[tid] = ((const float4*)(bias + N0))[tid];

    const float* Abase = Ap + ((size_t)(M0 + wm * 64 + kg * 4) * DOUT +
                               (N0 + wn * 32 + col16)) * RANK;

    auto stage = [&](int b, int kt) {
#pragma unroll
        for (int st = 0; st < 4; ++st) {
            int flat = st * 256 + tid;           // 128 rows x 8 chunks of 16B
            int row = flat >> 3, ch = flat & 7;
            int chs = ch ^ (row & 7);            // inverse-swizzled source
            const ushort* g = Xb + (size_t)(M0 + row) * DIN + kt + chs * 8;
            __builtin_amdgcn_global_load_lds(
                (const __attribute__((address_space(1))) void*)g,
                (__attribute__((address_space(3))) void*)(&As[b][flat * 8]), 16, 0, 0);
        }
#pragma unroll
        for (int st = 0; st < 2; ++st) {
            int flat = st * 256 + tid;           // 64 rows x 8 chunks
            int row = flat >> 3, ch = flat & 7;
            int chs = ch ^ (row & 7);
            const ushort* g = Wb + (size_t)(N0 + row) * DIN + kt + chs * 8;
            __builtin_amdgcn_global_load_lds(
                (const __attribute__((address_space(1))) void*)g,
                (__attribute__((address_space(3))) void*)(&Bs[b][flat * 8]), 16, 0, 0);
        }
    };

    // Prologue: stage tile 0; make sInter/sBias + buf0 visible.
    stage(0, 0);
    asm volatile("s_waitcnt vmcnt(0) lgkmcnt(0)" ::: "memory");
    __builtin_amdgcn_s_barrier();

    f32x4 acc[4][2] = {};

#pragma unroll
    for (int it = 0; it < 16; ++it) {
        const int cur = it & 1;
        if (it < 15) stage(cur ^ 1, (it + 1) * BK);

        // A-slice for output elements e = 2*it, 2*it+1 (static after unroll).
        const int nf = it >> 3, mf = (it >> 1) & 3, rg0 = (it & 1) * 2;
        const float* Ae0 = Abase + ((size_t)(mf * 16 + rg0) * DOUT + nf * 16) * RANK;
        const float* Ae1 = Ae0 + (size_t)DOUT * RANK;
        float4 a00 = ((const float4*)Ae0)[0];
        float4 a01 = ((const float4*)Ae0)[1];
        float4 a10 = ((const float4*)Ae1)[0];
        float4 a11 = ((const float4*)Ae1)[1];

        // MFMA on buf[cur] — swizzled ds_read offsets (conflict-free).
#pragma unroll
        for (int ks = 0; ks < 2; ++ks) {
            short8 a[4], b[2];
#pragma unroll
            for (int m4 = 0; m4 < 4; ++m4) {
                const int chs = (ks * 4 + kg) ^ c8;
                a[m4] = *(const short8*)(&As[cur][(wm * 64 + m4 * 16 + col16) * BK + chs * 8]);
            }
#pragma unroll
            for (int n2 = 0; n2 < 2; ++n2) {
                const int chs = (ks * 4 + kg) ^ c8;
                b[n2] = *(const short8*)(&Bs[cur][(wn * 32 + n2 * 16 + col16) * BK + chs * 8]);
            }
#pragma unroll
            for (int m4 = 0; m4 < 4; ++m4)
#pragma unroll
                for (int n2 = 0; n2 < 2; ++n2)
                    acc[m4][n2] = __builtin_amdgcn_mfma_f32_16x16x32_bf16(
                        a[m4], b[n2], acc[m4][n2], 0, 0, 0);
        }

        // Adaptation dot, straight into acc (static indices).
        {
            const int mloc0 = wm * 64 + mf * 16 + kg * 4 + rg0;
            const float4* iv0 = (const float4*)(sInter + mloc0 * 8);
            const float4* iv1 = (const float4*)(sInter + (mloc0 + 1) * 8);
            float4 i00 = iv0[0], i01 = iv0[1], i10 = iv1[0], i11 = iv1[1];
            float d0 = a00.x * i00.x + a00.y * i00.y + a00.z * i00.z + a00.w * i00.w +
                       a01.x * i01.x + a01.y * i01.y + a01.z * i01.z + a01.w * i01.w;
            float d1 = a10.x * i10.x + a10.y * i10.y + a10.z * i10.z + a10.w * i10.w +
                       a11.x * i11.x + a11.y * i11.y + a11.z * i11.z + a11.w * i11.w;
            acc[mf][nf][rg0] += d0;
            acc[mf][nf][rg0 + 1] += d1;
        }

        // Drain STAGE(t+1), then barrier (buf[cur] reads complete by MFMA deps).
        asm volatile("s_waitcnt vmcnt(0)" ::: "memory");
        __builtin_amdgcn_s_barrier();
    }

    // Epilogue: single write of out.
#pragma unroll
    for (int nf = 0; nf < 2; ++nf) {
        const int oc = wn * 32 + nf * 16 + col16;
        const int o = N0 + oc;
        const float bb = sBias[oc];
#pragma unroll
        for (int mf = 0; mf < 4; ++mf) {
#pragma unroll
            for (int rg = 0; rg < 4; ++rg) {
                const int m = M0 + wm * 64 + mf * 16 + kg * 4 + rg;
                out[(size_t)m * DOUT + o] = acc[mf][nf][rg] + bb;
            }
        }
    }
}

extern "C" void kernel_launch(void* const* d_in, const int* in_sizes, int n_in,
                              void* d_out, int out_size, void* d_ws, size_t ws_size,
                              hipStream_t stream) {
    const float* x    = (const float*)d_in[0];
    const float* Ap   = (const float*)d_in[1];
    const float* Bp   = (const float*)d_in[2];
    const float* W    = (const float*)d_in[3];
    const float* bias = (const float*)d_in[4];
    float* out = (float*)d_out;

    // ws: xb (8 MB) | Wb (2 MB) | inter (128 KB)
    ushort* xb = (ushort*)d_ws;
    ushort* Wb = xb + (size_t)TOKENS * DIN;
    float* inter = (float*)(Wb + (size_t)DOUT * DIN);

    hipLaunchKernelGGL(k_convert_w, dim3(DOUT * DIN / 1024), dim3(256), 0, stream, W, Wb);
    hipLaunchKernelGGL(k_inter, dim3(TOKENS), dim3(256), 0, stream, x, Bp, inter, xb);
    hipLaunchKernelGGL(k_gemm_fused, dim3((TOKENS / BM) * (DOUT / BN)), dim3(256), 0, stream,
                       xb, Wb, bias, inter, Ap, out);
}

// Round 11
// 71.883 us; speedup vs baseline: 1.0813x; 1.0223x over previous
//
#include <hip/hip_runtime.h>
#include <hip/hip_bf16.h>
#include <stdint.h>

#define TOKENS 4096
#define DIN 1024
#define DOUT 1024
#define RANK 8
#define BM 128
#define BN 64
#define BK 64

typedef __attribute__((ext_vector_type(4))) float f32x4;
typedef __attribute__((ext_vector_type(8))) short short8;

__device__ __forceinline__ unsigned short f2bf(float f) {
    union { float f; unsigned u; } v; v.f = f;
    unsigned r = v.u + 0x7FFFu + ((v.u >> 16) & 1u);
    return (unsigned short)(r >> 16);
}

// Fused: blocks [0,1024) -> per-WAVE token inter+xb (no barriers, no LDS);
// blocks [1024,1280) -> W fp32->bf16 conversion.
__global__ __launch_bounds__(256) void k_inter_cvt(const float* __restrict__ x,
                                                   const float* __restrict__ Bp,
                                                   const float* __restrict__ W,
                                                   float* __restrict__ inter,
                                                   ushort* __restrict__ xb,
                                                   ushort* __restrict__ Wb) {
    const int bid = blockIdx.x;
    const int tid = threadIdx.x;

    if (bid >= 1024) {
        // ---- W conversion: 256 blocks x 4096 floats ----
        const int b2 = bid - 1024;
        const float4* w4 = (const float4*)(W + (size_t)b2 * 4096);
        ushort4* o4 = (ushort4*)(Wb + (size_t)b2 * 4096);
#pragma unroll
        for (int j = 0; j < 4; ++j) {
            float4 v = w4[j * 256 + tid];
            ushort4 u;
            u.x = f2bf(v.x); u.y = f2bf(v.y); u.z = f2bf(v.z); u.w = f2bf(v.w);
            o4[j * 256 + tid] = u;
        }
        return;
    }

    // ---- per-wave token processing ----
    const int lane = tid & 63, wave = tid >> 6;
    const int t = bid * 4 + wave;

    const float4* x4 = (const float4*)(x + (size_t)t * DIN);
    float4 xv[4];
#pragma unroll
    for (int j = 0; j < 4; ++j) xv[j] = x4[j * 64 + lane];

    ushort4* xb4 = (ushort4*)(xb + (size_t)t * DIN);
#pragma unroll
    for (int j = 0; j < 4; ++j) {
        ushort4 u;
        u.x = f2bf(xv[j].x); u.y = f2bf(xv[j].y);
        u.z = f2bf(xv[j].z); u.w = f2bf(xv[j].w);
        xb4[j * 64 + lane] = u;
    }

    const float4* B4 = (const float4*)(Bp + (size_t)t * RANK * DIN);
    float acc[RANK];
#pragma unroll
    for (int r = 0; r < RANK; ++r) {
        float s = 0.f;
#pragma unroll
        for (int j = 0; j < 4; ++j) {
            float4 bv = B4[r * 256 + j * 64 + lane];
            s += bv.x * xv[j].x + bv.y * xv[j].y + bv.z * xv[j].z + bv.w * xv[j].w;
        }
        acc[r] = s;
    }

#pragma unroll
    for (int r = 0; r < RANK; ++r) {
#pragma unroll
        for (int off = 32; off > 0; off >>= 1)
            acc[r] += __shfl_xor(acc[r], off, 64);
    }

    if (lane == 0) {
        float4 lo, hi;
        lo.x = acc[0]; lo.y = acc[1]; lo.z = acc[2]; lo.w = acc[3];
        hi.x = acc[4]; hi.y = acc[5]; hi.z = acc[6]; hi.w = acc[7];
        float4* ip = (float4*)(inter + (size_t)t * RANK);
        ip[0] = lo; ip[1] = hi;
    }
}

// out[m,o] = bias[o] + Xb@Wb^T (bf16 MFMA) + sum_r inter[m,r]*A[m,o,r]
// UNCHANGED from R10 (dbuf + A-interleave + XCD swizzle + T2 LDS XOR-swizzle).
__global__ __launch_bounds__(256, 3) void k_gemm_fused(const ushort* __restrict__ Xb,
                                                       const ushort* __restrict__ Wb,
                                                       const float* __restrict__ bias,
                                                       const float* __restrict__ inter,
                                                       const float* __restrict__ Ap,
                                                       float* __restrict__ out) {
    __shared__ ushort As[2][BM * BK];   // 2 x 16 KB
    __shared__ ushort Bs[2][BN * BK];   // 2 x 8 KB
    __shared__ float sInter[BM * 8];    // 4 KB
    __shared__ float sBias[BN];

    const int tid = threadIdx.x;
    const int lane = tid & 63, wave = tid >> 6;
    const int wm = wave >> 1, wn = wave & 1;

    const int bid = blockIdx.x;
    const int swz = (bid & 7) * 64 + (bid >> 3);
    const int M0 = (swz >> 4) * BM;
    const int N0 = (swz & 15) * BN;

    const int col16 = lane & 15;
    const int kg = lane >> 4;
    const int c8 = col16 & 7;

    ((float4*)sInter)[tid] = ((const float4*)(inter + (size_t)M0 * RANK))[tid];
    if (tid < 16) ((float4*)sBias)[tid] = ((const float4*)(bias + N0))[tid];

    const float* Abase = Ap + ((size_t)(M0 + wm * 64 + kg * 4) * DOUT +
                               (N0 + wn * 32 + col16)) * RANK;

    auto stage = [&](int b, int kt) {
#pragma unroll
        for (int st = 0; st < 4; ++st) {
            int flat = st * 256 + tid;
            int row = flat >> 3, ch = flat & 7;
            int chs = ch ^ (row & 7);
            const ushort* g = Xb + (size_t)(M0 + row) * DIN + kt + chs * 8;
            __builtin_amdgcn_global_load_lds(
                (const __attribute__((address_space(1))) void*)g,
                (__attribute__((address_space(3))) void*)(&As[b][flat * 8]), 16, 0, 0);
        }
#pragma unroll
        for (int st = 0; st < 2; ++st) {
            int flat = st * 256 + tid;
            int row = flat >> 3, ch = flat & 7;
            int chs = ch ^ (row & 7);
            const ushort* g = Wb + (size_t)(N0 + row) * DIN + kt + chs * 8;
            __builtin_amdgcn_global_load_lds(
                (const __attribute__((address_space(1))) void*)g,
                (__attribute__((address_space(3))) void*)(&Bs[b][flat * 8]), 16, 0, 0);
        }
    };

    stage(0, 0);
    asm volatile("s_waitcnt vmcnt(0) lgkmcnt(0)" ::: "memory");
    __builtin_amdgcn_s_barrier();

    f32x4 acc[4][2] = {};

#pragma unroll
    for (int it = 0; it < 16; ++it) {
        const int cur = it & 1;
        if (it < 15) stage(cur ^ 1, (it + 1) * BK);

        const int nf = it >> 3, mf = (it >> 1) & 3, rg0 = (it & 1) * 2;
        const float* Ae0 = Abase + ((size_t)(mf * 16 + rg0) * DOUT + nf * 16) * RANK;
        const float* Ae1 = Ae0 + (size_t)DOUT * RANK;
        float4 a00 = ((const float4*)Ae0)[0];
        float4 a01 = ((const float4*)Ae0)[1];
        float4 a10 = ((const float4*)Ae1)[0];
        float4 a11 = ((const float4*)Ae1)[1];

#pragma unroll
        for (int ks = 0; ks < 2; ++ks) {
            short8 a[4], b[2];
#pragma unroll
            for (int m4 = 0; m4 < 4; ++m4) {
                const int chs = (ks * 4 + kg) ^ c8;
                a[m4] = *(const short8*)(&As[cur][(wm * 64 + m4 * 16 + col16) * BK + chs * 8]);
            }
#pragma unroll
            for (int n2 = 0; n2 < 2; ++n2) {
                const int chs = (ks * 4 + kg) ^ c8;
                b[n2] = *(const short8*)(&Bs[cur][(wn * 32 + n2 * 16 + col16) * BK + chs * 8]);
            }
#pragma unroll
            for (int m4 = 0; m4 < 4; ++m4)
#pragma unroll
                for (int n2 = 0; n2 < 2; ++n2)
                    acc[m4][n2] = __builtin_amdgcn_mfma_f32_16x16x32_bf16(
                        a[m4], b[n2], acc[m4][n2], 0, 0, 0);
        }

        {
            const int mloc0 = wm * 64 + mf * 16 + kg * 4 + rg0;
            const float4* iv0 = (const float4*)(sInter + mloc0 * 8);
            const float4* iv1 = (const float4*)(sInter + (mloc0 + 1) * 8);
            float4 i00 = iv0[0], i01 = iv0[1], i10 = iv1[0], i11 = iv1[1];
            float d0 = a00.x * i00.x + a00.y * i00.y + a00.z * i00.z + a00.w * i00.w +
                       a01.x * i01.x + a01.y * i01.y + a01.z * i01.z + a01.w * i01.w;
            float d1 = a10.x * i10.x + a10.y * i10.y + a10.z * i10.z + a10.w * i10.w +
                       a11.x * i11.x + a11.y * i11.y + a11.z * i11.z + a11.w * i11.w;
            acc[mf][nf][rg0] += d0;
            acc[mf][nf][rg0 + 1] += d1;
        }

        asm volatile("s_waitcnt vmcnt(0)" ::: "memory");
        __builtin_amdgcn_s_barrier();
    }

#pragma unroll
    for (int nf = 0; nf < 2; ++nf) {
        const int oc = wn * 32 + nf * 16 + col16;
        const int o = N0 + oc;
        const float bb = sBias[oc];
#pragma unroll
        for (int mf = 0; mf < 4; ++mf) {
#pragma unroll
            for (int rg = 0; rg < 4; ++rg) {
                const int m = M0 + wm * 64 + mf * 16 + kg * 4 + rg;
                out[(size_t)m * DOUT + o] = acc[mf][nf][rg] + bb;
            }
        }
    }
}

extern "C" void kernel_launch(void* const* d_in, const int* in_sizes, int n_in,
                              void* d_out, int out_size, void* d_ws, size_t ws_size,
                              hipStream_t stream) {
    const float* x    = (const float*)d_in[0];
    const float* Ap   = (const float*)d_in[1];
    const float* Bp   = (const float*)d_in[2];
    const float* W    = (const float*)d_in[3];
    const float* bias = (const float*)d_in[4];
    float* out = (float*)d_out;

    // ws: xb (8 MB) | Wb (2 MB) | inter (128 KB)
    ushort* xb = (ushort*)d_ws;
    ushort* Wb = xb + (size_t)TOKENS * DIN;
    float* inter = (float*)(Wb + (size_t)DOUT * DIN);

    hipLaunchKernelGGL(k_inter_cvt, dim3(1024 + 256), dim3(256), 0, stream,
                       x, Bp, W, inter, xb, Wb);
    hipLaunchKernelGGL(k_gemm_fused, dim3((TOKENS / BM) * (DOUT / BN)), dim3(256), 0, stream,
                       xb, Wb, bias, inter, Ap, out);
}

// Round 12
// 71.701 us; speedup vs baseline: 1.0840x; 1.0025x over previous
//
#include <hip/hip_runtime.h>
#include <hip/hip_bf16.h>
#include <stdint.h>

#define TOKENS 4096
#define DIN 1024
#define DOUT 1024
#define RANK 8
#define BM 128
#define BN 64
#define BK 64

typedef __attribute__((ext_vector_type(4))) float f32x4;
typedef __attribute__((ext_vector_type(8))) short short8;

__device__ __forceinline__ unsigned short f2bf(float f) {
    union { float f; unsigned u; } v; v.f = f;
    unsigned r = v.u + 0x7FFFu + ((v.u >> 16) & 1u);
    return (unsigned short)(r >> 16);
}

// Fused: blocks [0,1024) -> per-WAVE token inter+xb (no barriers, no LDS);
// blocks [1024,1280) -> W fp32->bf16 conversion.  (R11-proven)
__global__ __launch_bounds__(256) void k_inter_cvt(const float* __restrict__ x,
                                                   const float* __restrict__ Bp,
                                                   const float* __restrict__ W,
                                                   float* __restrict__ inter,
                                                   ushort* __restrict__ xb,
                                                   ushort* __restrict__ Wb) {
    const int bid = blockIdx.x;
    const int tid = threadIdx.x;

    if (bid >= 1024) {
        const int b2 = bid - 1024;
        const float4* w4 = (const float4*)(W + (size_t)b2 * 4096);
        ushort4* o4 = (ushort4*)(Wb + (size_t)b2 * 4096);
#pragma unroll
        for (int j = 0; j < 4; ++j) {
            float4 v = w4[j * 256 + tid];
            ushort4 u;
            u.x = f2bf(v.x); u.y = f2bf(v.y); u.z = f2bf(v.z); u.w = f2bf(v.w);
            o4[j * 256 + tid] = u;
        }
        return;
    }

    const int lane = tid & 63, wave = tid >> 6;
    const int t = bid * 4 + wave;

    const float4* x4 = (const float4*)(x + (size_t)t * DIN);
    float4 xv[4];
#pragma unroll
    for (int j = 0; j < 4; ++j) xv[j] = x4[j * 64 + lane];

    ushort4* xb4 = (ushort4*)(xb + (size_t)t * DIN);
#pragma unroll
    for (int j = 0; j < 4; ++j) {
        ushort4 u;
        u.x = f2bf(xv[j].x); u.y = f2bf(xv[j].y);
        u.z = f2bf(xv[j].z); u.w = f2bf(xv[j].w);
        xb4[j * 64 + lane] = u;
    }

    const float4* B4 = (const float4*)(Bp + (size_t)t * RANK * DIN);
    float acc[RANK];
#pragma unroll
    for (int r = 0; r < RANK; ++r) {
        float s = 0.f;
#pragma unroll
        for (int j = 0; j < 4; ++j) {
            float4 bv = B4[r * 256 + j * 64 + lane];
            s += bv.x * xv[j].x + bv.y * xv[j].y + bv.z * xv[j].z + bv.w * xv[j].w;
        }
        acc[r] = s;
    }

#pragma unroll
    for (int r = 0; r < RANK; ++r) {
#pragma unroll
        for (int off = 32; off > 0; off >>= 1)
            acc[r] += __shfl_xor(acc[r], off, 64);
    }

    if (lane == 0) {
        float4 lo, hi;
        lo.x = acc[0]; lo.y = acc[1]; lo.z = acc[2]; lo.w = acc[3];
        hi.x = acc[4]; hi.y = acc[5]; hi.z = acc[6]; hi.w = acc[7];
        float4* ip = (float4*)(inter + (size_t)t * RANK);
        ip[0] = lo; ip[1] = hi;
    }
}

// out[m,o] = bias[o] + Xb@Wb^T (bf16 MFMA) + sum_r inter[m,r]*A[m,o,r]
// BLOCK-FLAVOR SPECIALIZATION: even blocks run the barrier-free A-stream
// phase FIRST (seeding acc with bias+adaptation), odd blocks run it AFTER
// the GEMM K-loop. At any instant ~half the resident blocks stream A at
// fill-like BW while the other half do LDS/MFMA -> phase overlap across
// blocks. The A-phase is deeply unrolled (64 float4 loads, static acc
// indices), no barriers inside.
__global__ __launch_bounds__(256) void k_gemm_fused(const ushort* __restrict__ Xb,
                                                    const ushort* __restrict__ Wb,
                                                    const float* __restrict__ bias,
                                                    const float* __restrict__ inter,
                                                    const float* __restrict__ Ap,
                                                    float* __restrict__ out) {
    __shared__ ushort As[2][BM * BK];   // 2 x 16 KB
    __shared__ ushort Bs[2][BN * BK];   // 2 x 8 KB
    __shared__ float sInter[BM * 8];    // 4 KB

    const int tid = threadIdx.x;
    const int lane = tid & 63, wave = tid >> 6;
    const int wm = wave >> 1, wn = wave & 1;

    // XCD-aware bijective swizzle (512 % 8 == 0). flavor alternates within
    // each XCD's chunk -> every CU likely hosts one of each.
    const int bid = blockIdx.x;
    const int swz = (bid & 7) * 64 + (bid >> 3);
    const int M0 = (swz >> 4) * BM;
    const int N0 = (swz & 15) * BN;
    const int flavor = bid & 1;

    const int col16 = lane & 15;
    const int kg = lane >> 4;
    const int c8 = col16 & 7;

    // Stage inter tile into LDS (128 rows x 8 floats).
    ((float4*)sInter)[tid] = ((const float4*)(inter + (size_t)M0 * RANK))[tid];

    const float* Abase = Ap + ((size_t)(M0 + wm * 64 + kg * 4) * DOUT +
                               (N0 + wn * 32 + col16)) * RANK;

    f32x4 acc[4][2] = {};

    // Barrier-free A-stream phase: acc[mf][nf][rg] += bias[o] + dot(inter, A).
    auto adapt_phase = [&]() {
        const float bb0 = bias[N0 + wn * 32 + col16];
        const float bb1 = bias[N0 + wn * 32 + 16 + col16];
#pragma unroll
        for (int mf = 0; mf < 4; ++mf) {
#pragma unroll
            for (int rg = 0; rg < 4; ++rg) {
                const int mloc = wm * 64 + mf * 16 + kg * 4 + rg;
                const float4* iv = (const float4*)(sInter + mloc * 8);
                float4 i0 = iv[0], i1 = iv[1];
                const float* Ae = Abase + (size_t)(mf * 16 + rg) * DOUT * RANK;
#pragma unroll
                for (int nf = 0; nf < 2; ++nf) {
                    const float4* ap = (const float4*)(Ae + nf * 16 * RANK);
                    float4 a0 = ap[0], a1 = ap[1];
                    float d = a0.x * i0.x + a0.y * i0.y + a0.z * i0.z + a0.w * i0.w +
                              a1.x * i1.x + a1.y * i1.y + a1.z * i1.z + a1.w * i1.w;
                    acc[mf][nf][rg] += d + (nf ? bb1 : bb0);
                }
            }
        }
    };

    auto stage = [&](int b, int kt) {
#pragma unroll
        for (int st = 0; st < 4; ++st) {
            int flat = st * 256 + tid;           // 128 rows x 8 chunks of 16B
            int row = flat >> 3, ch = flat & 7;
            int chs = ch ^ (row & 7);            // inverse-swizzled source (T2)
            const ushort* g = Xb + (size_t)(M0 + row) * DIN + kt + chs * 8;
            __builtin_amdgcn_global_load_lds(
                (const __attribute__((address_space(1))) void*)g,
                (__attribute__((address_space(3))) void*)(&As[b][flat * 8]), 16, 0, 0);
        }
#pragma unroll
        for (int st = 0; st < 2; ++st) {
            int flat = st * 256 + tid;           // 64 rows x 8 chunks
            int row = flat >> 3, ch = flat & 7;
            int chs = ch ^ (row & 7);
            const ushort* g = Wb + (size_t)(N0 + row) * DIN + kt + chs * 8;
            __builtin_amdgcn_global_load_lds(
                (const __attribute__((address_space(1))) void*)g,
                (__attribute__((address_space(3))) void*)(&Bs[b][flat * 8]), 16, 0, 0);
        }
    };

    if (flavor == 0) {
        __syncthreads();      // sInter visible
        adapt_phase();        // stream A while odd blocks do GEMM
    }

    // GEMM K-loop (R10 structure; T2 swizzled reads; no A coupling).
    stage(0, 0);
    asm volatile("s_waitcnt vmcnt(0) lgkmcnt(0)" ::: "memory");
    __builtin_amdgcn_s_barrier();

#pragma unroll
    for (int it = 0; it < 16; ++it) {
        const int cur = it & 1;
        if (it < 15) stage(cur ^ 1, (it + 1) * BK);

#pragma unroll
        for (int ks = 0; ks < 2; ++ks) {
            short8 a[4], b[2];
#pragma unroll
            for (int m4 = 0; m4 < 4; ++m4) {
                const int chs = (ks * 4 + kg) ^ c8;
                a[m4] = *(const short8*)(&As[cur][(wm * 64 + m4 * 16 + col16) * BK + chs * 8]);
            }
#pragma unroll
            for (int n2 = 0; n2 < 2; ++n2) {
                const int chs = (ks * 4 + kg) ^ c8;
                b[n2] = *(const short8*)(&Bs[cur][(wn * 32 + n2 * 16 + col16) * BK + chs * 8]);
            }
#pragma unroll
            for (int m4 = 0; m4 < 4; ++m4)
#pragma unroll
                for (int n2 = 0; n2 < 2; ++n2)
                    acc[m4][n2] = __builtin_amdgcn_mfma_f32_16x16x32_bf16(
                        a[m4], b[n2], acc[m4][n2], 0, 0, 0);
        }

        asm volatile("s_waitcnt vmcnt(0)" ::: "memory");
        __builtin_amdgcn_s_barrier();
    }

    if (flavor == 1) {
        adapt_phase();        // stream A while even blocks (started later) GEMM
    }

    // Epilogue: single write (bias+adaptation already inside acc).
#pragma unroll
    for (int nf = 0; nf < 2; ++nf) {
        const int o = N0 + wn * 32 + nf * 16 + col16;
#pragma unroll
        for (int mf = 0; mf < 4; ++mf) {
#pragma unroll
            for (int rg = 0; rg < 4; ++rg) {
                const int m = M0 + wm * 64 + mf * 16 + kg * 4 + rg;
                out[(size_t)m * DOUT + o] = acc[mf][nf][rg];
            }
        }
    }
}

extern "C" void kernel_launch(void* const* d_in, const int* in_sizes, int n_in,
                              void* d_out, int out_size, void* d_ws, size_t ws_size,
                              hipStream_t stream) {
    const float* x    = (const float*)d_in[0];
    const float* Ap   = (const float*)d_in[1];
    const float* Bp   = (const float*)d_in[2];
    const float* W    = (const float*)d_in[3];
    const float* bias = (const float*)d_in[4];
    float* out = (float*)d_out;

    // ws: xb (8 MB) | Wb (2 MB) | inter (128 KB)
    ushort* xb = (ushort*)d_ws;
    ushort* Wb = xb + (size_t)TOKENS * DIN;
    float* inter = (float*)(Wb + (size_t)DOUT * DIN);

    hipLaunchKernelGGL(k_inter_cvt, dim3(1024 + 256), dim3(256), 0, stream,
                       x, Bp, W, inter, xb, Wb);
    hipLaunchKernelGGL(k_gemm_fused, dim3((TOKENS / BM) * (DOUT / BN)), dim3(256), 0, stream,
                       xb, Wb, bias, inter, Ap, out);
}